// Round 1
// baseline (541.788 us; speedup 1.0000x reference)
//
#include <hip/hip_runtime.h>

#define NN 20000
#define IN_DIM 256
#define HID 128
#define OUT_DIM 64
#define N_LAYERS 4
#define N_PATHS 8
#define PATH_LEN 8
#define N_TYPES 2

// ---------------------------------------------------------------------------
// Generic tiled fp32 GEMM: C = epilogue(A[M,K] @ W[N,K]^T)
// EPI 0: C = relu(acc + bias[n])
// EPI 1: C = 0.8*relu(acc) + 0.1*pre + 0.1*in0   (layer fc, no bias)
// BM=32, BK=64. threads = 256 arranged (N/TN) x (BM/TM).
// ---------------------------------------------------------------------------
template <int N, int K, int EPI>
__global__ __launch_bounds__(256) void gemm_relu(
    const float* __restrict__ A,
    const float* __restrict__ W,
    const float* __restrict__ bias,
    const float* __restrict__ pre,
    const float* __restrict__ in0,
    float* __restrict__ C,
    int M)
{
    constexpr int BM = 32;
    constexpr int BK = 64;
    constexpr int TM = 4;
    constexpr int TN = (N == 128) ? 4 : 2;
    constexpr int TX = N / TN;   // 32
    static_assert(TX * (BM / TM) == 256, "thread layout");

    __shared__ float As[BM][BK + 1];
    __shared__ float Ws[BK][N + 1];

    const int tid = threadIdx.x;
    const int tx = tid % TX;          // n-dim
    const int ty = tid / TX;          // m-dim (0..7)
    const int m0 = blockIdx.x * BM;

    float acc[TM][TN];
#pragma unroll
    for (int i = 0; i < TM; ++i)
#pragma unroll
        for (int j = 0; j < TN; ++j) acc[i][j] = 0.f;

    for (int k0 = 0; k0 < K; k0 += BK) {
        // stage A tile (coalesced along k), pad +1 breaks write conflicts
#pragma unroll
        for (int i = tid; i < BM * BK; i += 256) {
            int m = i / BK, k = i % BK;
            As[m][k] = A[(long)(m0 + m) * K + k0 + k];
        }
        // stage W tile transposed: Ws[k][n] = W[n][k0+k]
#pragma unroll
        for (int i = tid; i < BK * N; i += 256) {
            int n = i / BK, k = i % BK;
            Ws[k][n] = W[(long)n * K + k0 + k];
        }
        __syncthreads();

#pragma unroll
        for (int k = 0; k < BK; ++k) {
            float a[TM], b[TN];
#pragma unroll
            for (int i = 0; i < TM; ++i) a[i] = As[ty * TM + i][k];
#pragma unroll
            for (int j = 0; j < TN; ++j) b[j] = Ws[k][tx * TN + j];
#pragma unroll
            for (int i = 0; i < TM; ++i)
#pragma unroll
                for (int j = 0; j < TN; ++j) acc[i][j] += a[i] * b[j];
        }
        __syncthreads();
    }

#pragma unroll
    for (int i = 0; i < TM; ++i) {
        int gm = m0 + ty * TM + i;
        if (gm >= M) continue;
#pragma unroll
        for (int j = 0; j < TN; ++j) {
            int n = tx * TN + j;
            float v = acc[i][j];
            if (EPI == 0) {
                v += bias[n];
                v = v > 0.f ? v : 0.f;
            } else {
                v = v > 0.f ? v : 0.f;
                v = 0.8f * v + 0.1f * pre[(long)gm * N + n] + 0.1f * in0[(long)gm * N + n];
            }
            C[(long)gm * N + n] = v;
        }
    }
}

// ---------------------------------------------------------------------------
// Gather + weighted path sum + per-type mean.
// fout[n, e*HID + h] = (1/count_e) * sum_{p: type(p)=e} sum_l feats[paths[p,n,l], h] * pw[e,l,h]
// Block: 256 threads = 2 nodes x 128 h-lanes.
// ---------------------------------------------------------------------------
__global__ __launch_bounds__(256) void gather_kernel(
    const float* __restrict__ feats,   // NN x HID
    const int* __restrict__ paths,     // P x NN x L
    const int* __restrict__ ptypes,    // P
    const float* __restrict__ pw,      // N_TYPES x L x HID
    float* __restrict__ fout)          // NN x (N_TYPES*HID)
{
    const int tid = threadIdx.x;
    const int local_node = tid >> 7;   // 0..1
    const int h = tid & 127;
    const int n = blockIdx.x * 2 + local_node;

    __shared__ int idxs[2][N_PATHS * PATH_LEN];

    // stage the 64 path indices of each of the 2 nodes (128 ints)
    if (tid < 2 * N_PATHS * PATH_LEN) {
        int node = tid >> 6;
        int j = tid & 63;
        int p = j >> 3, l = j & 7;
        int gn = blockIdx.x * 2 + node;
        idxs[node][j] = paths[((long)p * NN + gn) * PATH_LEN + l];
    }
    __syncthreads();

    // path types (uniform, L1/scalar cached)
    int pt[N_PATHS];
#pragma unroll
    for (int p = 0; p < N_PATHS; ++p) pt[p] = ptypes[p];

    // per-h path weights for both types
    float wv0[PATH_LEN], wv1[PATH_LEN];
#pragma unroll
    for (int l = 0; l < PATH_LEN; ++l) {
        wv0[l] = pw[(0 * PATH_LEN + l) * HID + h];
        wv1[l] = pw[(1 * PATH_LEN + l) * HID + h];
    }

    float acc0 = 0.f, acc1 = 0.f;
    int c0 = 0, c1 = 0;
#pragma unroll
    for (int p = 0; p < N_PATHS; ++p) {
        float local = 0.f;
        const int t = pt[p];                     // wave-uniform
#pragma unroll
        for (int l = 0; l < PATH_LEN; ++l) {
            int idx = idxs[local_node][p * PATH_LEN + l];
            float v = feats[(long)idx * HID + h];
            float w = (t == 0) ? wv0[l] : wv1[l];
            local += v * w;
        }
        if (t == 0) { acc0 += local; c0++; }
        else        { acc1 += local; c1++; }
    }

    float r0 = c0 ? acc0 / (float)c0 : 0.f;
    float r1 = c1 ? acc1 / (float)c1 : 0.f;
    fout[(long)n * (N_TYPES * HID) + h] = r0;
    fout[(long)n * (N_TYPES * HID) + HID + h] = r1;
}

// ---------------------------------------------------------------------------
extern "C" void kernel_launch(void* const* d_in, const int* in_sizes, int n_in,
                              void* d_out, int out_size, void* d_ws, size_t ws_size,
                              hipStream_t stream)
{
    const float* input_x     = (const float*)d_in[0];
    const int*   paths       = (const int*)d_in[1];
    const int*   path_types  = (const int*)d_in[2];
    const float* fc_in_w     = (const float*)d_in[3];
    const float* fc_in_b     = (const float*)d_in[4];
    const float* fc_out_w    = (const float*)d_in[5];
    const float* fc_out_b    = (const float*)d_in[6];
    const float* layer_fc_w  = (const float*)d_in[7];
    const float* path_weights= (const float*)d_in[8];
    float* out = (float*)d_out;

    float* ws = (float*)d_ws;
    float* in_feats = ws;                       // NN*HID
    float* featsA   = ws + (long)NN * HID;      // NN*HID
    float* featsB   = ws + (long)2 * NN * HID;  // NN*HID
    float* fout     = ws + (long)3 * NN * HID;  // NN*2*HID

    const int GEMM_GRID = NN / 32;   // 625, exact

    // in_feats = relu(x @ Win^T + b)
    gemm_relu<HID, IN_DIM, 0><<<GEMM_GRID, 256, 0, stream>>>(
        input_x, fc_in_w, fc_in_b, nullptr, nullptr, in_feats, NN);

    const float* src = in_feats;
    float* dsts[N_LAYERS] = {featsA, featsB, featsA, featsB};
    for (int i = 0; i < N_LAYERS; ++i) {
        gather_kernel<<<NN / 2, 256, 0, stream>>>(
            src, paths, path_types,
            path_weights + (long)i * N_TYPES * PATH_LEN * HID, fout);
        gemm_relu<HID, N_TYPES * HID, 1><<<GEMM_GRID, 256, 0, stream>>>(
            fout, layer_fc_w + (long)i * HID * N_TYPES * HID, nullptr,
            src, in_feats, dsts[i], NN);
        src = dsts[i];
    }

    // out = relu(feats @ Wout^T + b)
    gemm_relu<OUT_DIM, HID, 0><<<GEMM_GRID, 256, 0, stream>>>(
        src, fc_out_w, fc_out_b, nullptr, nullptr, out, NN);
}

// Round 2
// 241.713 us; speedup vs baseline: 2.2415x; 2.2415x over previous
//
#include <hip/hip_runtime.h>

#define NN 20000
#define IN_DIM 256
#define HID 128
#define OUT_DIM 64
#define N_LAYERS 4
#define N_PATHS 8
#define PATH_LEN 8
#define N_TYPES 2

typedef __attribute__((ext_vector_type(8))) short bf16x8;
typedef __attribute__((ext_vector_type(4))) float f32x4;

__device__ __forceinline__ float bf2f(ushort u) {
    union { uint u; float f; } c; c.u = ((uint)u) << 16; return c.f;
}
__device__ __forceinline__ ushort f2bf(float f) {
    union { float f; uint u; } c; c.f = f;
    uint u = c.u;
    uint lsb = (u >> 16) & 1;
    u += 0x7fffu + lsb;          // round-to-nearest-even (inputs are finite)
    return (ushort)(u >> 16);
}

// ---------------------------------------------------------------------------
// fp32 -> bf16 conversion, 4 elems/thread
// ---------------------------------------------------------------------------
__global__ __launch_bounds__(256) void cvt_f2bf(const float* __restrict__ src,
                                                ushort* __restrict__ dst, int n4)
{
    int i = blockIdx.x * 256 + threadIdx.x;
    if (i >= n4) return;
    float4 v = *(const float4*)(src + (long)i * 4);
    ushort4 o;
    o.x = f2bf(v.x); o.y = f2bf(v.y); o.z = f2bf(v.z); o.w = f2bf(v.w);
    *(ushort4*)(dst + (long)i * 4) = o;
}

// ---------------------------------------------------------------------------
// bf16 MFMA GEMM: C = epilogue(A[M,K] @ W[N,K]^T), fp32 accumulate.
// BM=64, BK=64, 4 waves (2x2), each wave computes 32 x N/2.
// MFMA 16x16x32 bf16. LDS XOR-swizzle: elem_idx ^= (row&7)<<3 (16B granules)
// so stride-128B fragment reads are bank-conflict-free (T2).
// A-frag: lane holds A[l&15][(l>>4)*8+j]; B-frag: W[l&15][(l>>4)*8+j];
// D-frag j: row=(l>>4)*4+j, col=l&15  [m89-verified layout].
// EPI 0: bf16 out = relu(acc + bias[n])
// EPI 1: bf16 out = 0.8*relu(acc) + 0.1*pre + 0.1*in0
// EPI 2: f32  out = relu(acc + bias[n])
// ---------------------------------------------------------------------------
template <int N, int K, int EPI>
__global__ __launch_bounds__(256) void gemm_mfma(
    const ushort* __restrict__ A,     // [M][K] bf16
    const ushort* __restrict__ W,     // [N][K] bf16
    const float* __restrict__ bias,   // [N] f32
    const ushort* __restrict__ pre,   // [M][N] bf16 (EPI 1)
    const ushort* __restrict__ in0,   // [M][N] bf16 (EPI 1)
    void* __restrict__ Cout,
    int M)
{
    constexpr int BM = 64, BK = 64;
    constexpr int NC = N / 32;              // 4 (N=128) or 2 (N=64)

    __shared__ short As[BM * BK];
    __shared__ short Ws[N * BK];

    const int tid = threadIdx.x;
    const int lane = tid & 63;
    const int w = tid >> 6;
    const int wr = w >> 1, wc = w & 1;
    const int m0 = blockIdx.x * BM;
    const int l15 = lane & 15, l4 = lane >> 4;

    f32x4 acc[2][NC];
#pragma unroll
    for (int mr = 0; mr < 2; ++mr)
#pragma unroll
        for (int nc = 0; nc < NC; ++nc)
#pragma unroll
            for (int j = 0; j < 4; ++j) acc[mr][nc][j] = 0.f;

    for (int k0 = 0; k0 < K; k0 += BK) {
        // stage A tile: 512 x 16B chunks, 2 per thread
#pragma unroll
        for (int c = tid; c < BM * BK / 8; c += 256) {
            int r = c >> 3, kc = c & 7;
            int gr = m0 + r; if (gr >= M) gr = M - 1;   // clamp tail
            bf16x8 v = *(const bf16x8*)(A + (long)gr * K + k0 + kc * 8);
            int di = (r * BK + kc * 8) ^ ((r & 7) << 3);
            *(bf16x8*)&As[di] = v;
        }
        // stage W tile
#pragma unroll
        for (int c = tid; c < N * BK / 8; c += 256) {
            int r = c >> 3, kc = c & 7;
            bf16x8 v = *(const bf16x8*)(W + (long)r * K + k0 + kc * 8);
            int di = (r * BK + kc * 8) ^ ((r & 7) << 3);
            *(bf16x8*)&Ws[di] = v;
        }
        __syncthreads();

#pragma unroll
        for (int ks = 0; ks < 2; ++ks) {
            bf16x8 av[2], bv[NC];
            const int kk = ks * 32 + l4 * 8;
#pragma unroll
            for (int mr = 0; mr < 2; ++mr) {
                int r = wr * 32 + mr * 16 + l15;
                av[mr] = *(const bf16x8*)&As[(r * BK + kk) ^ ((r & 7) << 3)];
            }
#pragma unroll
            for (int nc = 0; nc < NC; ++nc) {
                int r = wc * (N / 2) + nc * 16 + l15;
                bv[nc] = *(const bf16x8*)&Ws[(r * BK + kk) ^ ((r & 7) << 3)];
            }
#pragma unroll
            for (int mr = 0; mr < 2; ++mr)
#pragma unroll
                for (int nc = 0; nc < NC; ++nc)
                    acc[mr][nc] = __builtin_amdgcn_mfma_f32_16x16x32_bf16(
                        av[mr], bv[nc], acc[mr][nc], 0, 0, 0);
        }
        __syncthreads();
    }

#pragma unroll
    for (int mr = 0; mr < 2; ++mr) {
#pragma unroll
        for (int nc = 0; nc < NC; ++nc) {
            int gn = wc * (N / 2) + nc * 16 + l15;
#pragma unroll
            for (int j = 0; j < 4; ++j) {
                int gm = m0 + wr * 32 + mr * 16 + l4 * 4 + j;
                if (gm >= M) continue;
                float v = acc[mr][nc][j];
                if (EPI == 0) {
                    v += bias[gn];
                    v = fmaxf(v, 0.f);
                    ((ushort*)Cout)[(long)gm * N + gn] = f2bf(v);
                } else if (EPI == 1) {
                    v = fmaxf(v, 0.f);
                    v = 0.8f * v + 0.1f * bf2f(pre[(long)gm * N + gn])
                                 + 0.1f * bf2f(in0[(long)gm * N + gn]);
                    ((ushort*)Cout)[(long)gm * N + gn] = f2bf(v);
                } else {
                    v += bias[gn];
                    v = fmaxf(v, 0.f);
                    ((float*)Cout)[(long)gm * N + gn] = v;
                }
            }
        }
    }
}

// ---------------------------------------------------------------------------
// Gather + weighted path-sum + per-type mean, bf16 feats.
// Block = 256 threads = 4 nodes x 64 lanes; lane owns h = {2*lane, 2*lane+1}
// (one packed uint per gather). Wave-uniform type branch, statically-indexed
// weight registers (no scratch).
// ---------------------------------------------------------------------------
__global__ __launch_bounds__(256) void gather_bf16(
    const uint* __restrict__ feats_u,   // [NN][64] (bf16x2 packed)
    const int* __restrict__ paths,      // [P][NN][L]
    const int* __restrict__ ptypes,     // [P]
    const float* __restrict__ pw,       // [2][L][HID] f32
    uint* __restrict__ fout_u)          // [NN][128] (bf16x2 packed)
{
    const int tid = threadIdx.x;
    const int node = tid >> 6;
    const int lane = tid & 63;
    const int n = blockIdx.x * 4 + node;

    __shared__ int idxs[4][N_PATHS * PATH_LEN];
    {
        int p = lane >> 3, l = lane & 7;
        idxs[node][lane] = paths[((long)p * NN + n) * PATH_LEN + l];
    }
    __syncthreads();

    // per-lane weights for both types (static register arrays)
    float2 wv0[PATH_LEN], wv1[PATH_LEN];
#pragma unroll
    for (int l = 0; l < PATH_LEN; ++l) {
        wv0[l] = *(const float2*)&pw[(0 * PATH_LEN + l) * HID + lane * 2];
        wv1[l] = *(const float2*)&pw[(1 * PATH_LEN + l) * HID + lane * 2];
    }

    float a0x = 0.f, a0y = 0.f, a1x = 0.f, a1y = 0.f;
    int c0 = 0, c1 = 0;
#pragma unroll
    for (int p = 0; p < N_PATHS; ++p) {
        int t = ptypes[p];                       // wave-uniform
        if (t == 0) {
            float sx = 0.f, sy = 0.f;
#pragma unroll
            for (int l = 0; l < PATH_LEN; ++l) {
                int idx = idxs[node][p * PATH_LEN + l];
                uint v = feats_u[(long)idx * 64 + lane];
                sx += bf2f((ushort)(v & 0xffff)) * wv0[l].x;
                sy += bf2f((ushort)(v >> 16))    * wv0[l].y;
            }
            a0x += sx; a0y += sy; ++c0;
        } else {
            float sx = 0.f, sy = 0.f;
#pragma unroll
            for (int l = 0; l < PATH_LEN; ++l) {
                int idx = idxs[node][p * PATH_LEN + l];
                uint v = feats_u[(long)idx * 64 + lane];
                sx += bf2f((ushort)(v & 0xffff)) * wv1[l].x;
                sy += bf2f((ushort)(v >> 16))    * wv1[l].y;
            }
            a1x += sx; a1y += sy; ++c1;
        }
    }

    float i0 = c0 ? 1.f / (float)c0 : 0.f;
    float i1 = c1 ? 1.f / (float)c1 : 0.f;
    uint r0 = (uint)f2bf(a0x * i0) | ((uint)f2bf(a0y * i0) << 16);
    uint r1 = (uint)f2bf(a1x * i1) | ((uint)f2bf(a1y * i1) << 16);
    fout_u[(long)n * 128 + lane] = r0;
    fout_u[(long)n * 128 + 64 + lane] = r1;
}

// ---------------------------------------------------------------------------
extern "C" void kernel_launch(void* const* d_in, const int* in_sizes, int n_in,
                              void* d_out, int out_size, void* d_ws, size_t ws_size,
                              hipStream_t stream)
{
    const float* input_x      = (const float*)d_in[0];
    const int*   paths        = (const int*)d_in[1];
    const int*   path_types   = (const int*)d_in[2];
    const float* fc_in_w      = (const float*)d_in[3];
    const float* fc_in_b      = (const float*)d_in[4];
    const float* fc_out_w     = (const float*)d_in[5];
    const float* fc_out_b     = (const float*)d_in[6];
    const float* layer_fc_w   = (const float*)d_in[7];
    const float* path_weights = (const float*)d_in[8];
    float* out = (float*)d_out;

    char* p = (char*)d_ws;
    ushort* x_bf     = (ushort*)p; p += (long)NN * IN_DIM * 2;            // 10.24 MB
    ushort* w_in     = (ushort*)p; p += HID * IN_DIM * 2;                 // 64 KB
    ushort* w_layer  = (ushort*)p; p += N_LAYERS * HID * N_TYPES * HID * 2; // 256 KB
    ushort* w_out    = (ushort*)p; p += OUT_DIM * HID * 2;                // 16 KB
    ushort* in_feats = (ushort*)p; p += (long)NN * HID * 2;               // 5.12 MB
    ushort* featsA   = (ushort*)p; p += (long)NN * HID * 2;
    ushort* featsB   = (ushort*)p; p += (long)NN * HID * 2;
    ushort* fout     = (ushort*)p; p += (long)NN * N_TYPES * HID * 2;     // 10.24 MB

    // weight / input conversion to bf16
    cvt_f2bf<<<(NN * IN_DIM / 4 + 255) / 256, 256, 0, stream>>>(input_x, x_bf, NN * IN_DIM / 4);
    cvt_f2bf<<<(HID * IN_DIM / 4 + 255) / 256, 256, 0, stream>>>(fc_in_w, w_in, HID * IN_DIM / 4);
    cvt_f2bf<<<(N_LAYERS * HID * N_TYPES * HID / 4 + 255) / 256, 256, 0, stream>>>(
        layer_fc_w, w_layer, N_LAYERS * HID * N_TYPES * HID / 4);
    cvt_f2bf<<<(OUT_DIM * HID / 4 + 255) / 256, 256, 0, stream>>>(fc_out_w, w_out, OUT_DIM * HID / 4);

    const int GG = (NN + 63) / 64;   // 313

    gemm_mfma<HID, IN_DIM, 0><<<GG, 256, 0, stream>>>(
        x_bf, w_in, fc_in_b, nullptr, nullptr, in_feats, NN);

    const ushort* src = in_feats;
    ushort* dsts[N_LAYERS] = {featsA, featsB, featsA, featsB};
    for (int i = 0; i < N_LAYERS; ++i) {
        gather_bf16<<<NN / 4, 256, 0, stream>>>(
            (const uint*)src, paths, path_types,
            path_weights + (long)i * N_TYPES * PATH_LEN * HID, (uint*)fout);
        gemm_mfma<HID, N_TYPES * HID, 1><<<GG, 256, 0, stream>>>(
            fout, w_layer + (long)i * HID * N_TYPES * HID, nullptr,
            src, in_feats, dsts[i], NN);
        src = dsts[i];
    }

    gemm_mfma<OUT_DIM, HID, 2><<<GG, 256, 0, stream>>>(
        src, w_out, fc_out_b, nullptr, nullptr, out, NN);
}

// Round 3
// 211.043 us; speedup vs baseline: 2.5672x; 1.1453x over previous
//
#include <hip/hip_runtime.h>

#define NN 20000
#define IN_DIM 256
#define HID 128
#define OUT_DIM 64
#define N_LAYERS 4
#define N_PATHS 8
#define PATH_LEN 8
#define N_TYPES 2

typedef __attribute__((ext_vector_type(8))) short bf16x8;
typedef __attribute__((ext_vector_type(4))) float f32x4;

__device__ __forceinline__ float bf2f(ushort u) {
    union { uint u; float f; } c; c.u = ((uint)u) << 16; return c.f;
}
__device__ __forceinline__ ushort f2bf(float f) {
    union { float f; uint u; } c; c.f = f;
    uint u = c.u;
    uint lsb = (u >> 16) & 1;
    u += 0x7fffu + lsb;          // round-to-nearest-even (inputs are finite)
    return (ushort)(u >> 16);
}

// ---------------------------------------------------------------------------
// bf16 MFMA GEMM: C = epilogue(A[M,K] @ W[N,K]^T), fp32 accumulate.
// BM=64, BK=64, 4 waves (2x2), wave computes 32 x N/2. MFMA 16x16x32 bf16.
// LDS XOR-swizzle on 16B granules: elem ^= (row&7)<<3  (T2, conflict-free).
// AF32/WF32: operand is fp32 in global, converted to bf16 while staging.
// EPI 0: bf16 out = relu(acc + bias[n])
// EPI 1: bf16 out = 0.8*relu(acc) + 0.1*pre + 0.1*in0
// EPI 2: f32  out = relu(acc + bias[n])
// ---------------------------------------------------------------------------
template <int N, int K, int EPI, bool AF32, bool WF32>
__global__ __launch_bounds__(256) void gemm_mfma(
    const void* __restrict__ Ap,
    const void* __restrict__ Wp,
    const float* __restrict__ bias,
    const ushort* __restrict__ pre,
    const ushort* __restrict__ in0,
    void* __restrict__ Cout,
    int M)
{
    constexpr int BM = 64, BK = 64;
    constexpr int NC = N / 32;              // 4 (N=128) or 2 (N=64)

    __shared__ short As[BM * BK];
    __shared__ short Ws[N * BK];

    const int tid = threadIdx.x;
    const int lane = tid & 63;
    const int w = tid >> 6;
    const int wr = w >> 1, wc = w & 1;
    const int m0 = blockIdx.x * BM;
    const int l15 = lane & 15, l4 = lane >> 4;

    f32x4 acc[2][NC];
#pragma unroll
    for (int mr = 0; mr < 2; ++mr)
#pragma unroll
        for (int nc = 0; nc < NC; ++nc)
#pragma unroll
            for (int j = 0; j < 4; ++j) acc[mr][nc][j] = 0.f;

    for (int k0 = 0; k0 < K; k0 += BK) {
        // ---- stage A tile (8-elem granules, 2 per thread) ----
#pragma unroll
        for (int c = tid; c < BM * BK / 8; c += 256) {
            int r = c >> 3, kc = c & 7;
            int gr = m0 + r; if (gr >= M) gr = M - 1;   // clamp tail
            bf16x8 v;
            if constexpr (AF32) {
                const float* Af = (const float*)Ap;
                float4 v0 = *(const float4*)(Af + (long)gr * K + k0 + kc * 8);
                float4 v1 = *(const float4*)(Af + (long)gr * K + k0 + kc * 8 + 4);
                v[0] = (short)f2bf(v0.x); v[1] = (short)f2bf(v0.y);
                v[2] = (short)f2bf(v0.z); v[3] = (short)f2bf(v0.w);
                v[4] = (short)f2bf(v1.x); v[5] = (short)f2bf(v1.y);
                v[6] = (short)f2bf(v1.z); v[7] = (short)f2bf(v1.w);
            } else {
                v = *(const bf16x8*)((const ushort*)Ap + (long)gr * K + k0 + kc * 8);
            }
            int di = (r * BK + kc * 8) ^ ((r & 7) << 3);
            *(bf16x8*)&As[di] = v;
        }
        // ---- stage W tile ----
#pragma unroll
        for (int c = tid; c < N * BK / 8; c += 256) {
            int r = c >> 3, kc = c & 7;
            bf16x8 v;
            if constexpr (WF32) {
                const float* Wf = (const float*)Wp;
                float4 v0 = *(const float4*)(Wf + (long)r * K + k0 + kc * 8);
                float4 v1 = *(const float4*)(Wf + (long)r * K + k0 + kc * 8 + 4);
                v[0] = (short)f2bf(v0.x); v[1] = (short)f2bf(v0.y);
                v[2] = (short)f2bf(v0.z); v[3] = (short)f2bf(v0.w);
                v[4] = (short)f2bf(v1.x); v[5] = (short)f2bf(v1.y);
                v[6] = (short)f2bf(v1.z); v[7] = (short)f2bf(v1.w);
            } else {
                v = *(const bf16x8*)((const ushort*)Wp + (long)r * K + k0 + kc * 8);
            }
            int di = (r * BK + kc * 8) ^ ((r & 7) << 3);
            *(bf16x8*)&Ws[di] = v;
        }
        __syncthreads();

#pragma unroll
        for (int ks = 0; ks < 2; ++ks) {
            bf16x8 av[2], bv[NC];
            const int kk = ks * 32 + l4 * 8;
#pragma unroll
            for (int mr = 0; mr < 2; ++mr) {
                int r = wr * 32 + mr * 16 + l15;
                av[mr] = *(const bf16x8*)&As[(r * BK + kk) ^ ((r & 7) << 3)];
            }
#pragma unroll
            for (int nc = 0; nc < NC; ++nc) {
                int r = wc * (N / 2) + nc * 16 + l15;
                bv[nc] = *(const bf16x8*)&Ws[(r * BK + kk) ^ ((r & 7) << 3)];
            }
#pragma unroll
            for (int mr = 0; mr < 2; ++mr)
#pragma unroll
                for (int nc = 0; nc < NC; ++nc)
                    acc[mr][nc] = __builtin_amdgcn_mfma_f32_16x16x32_bf16(
                        av[mr], bv[nc], acc[mr][nc], 0, 0, 0);
        }
        __syncthreads();
    }

#pragma unroll
    for (int mr = 0; mr < 2; ++mr) {
#pragma unroll
        for (int nc = 0; nc < NC; ++nc) {
            int gn = wc * (N / 2) + nc * 16 + l15;
#pragma unroll
            for (int j = 0; j < 4; ++j) {
                int gm = m0 + wr * 32 + mr * 16 + l4 * 4 + j;
                if (gm >= M) continue;
                float v = acc[mr][nc][j];
                if (EPI == 0) {
                    v += bias[gn];
                    v = fmaxf(v, 0.f);
                    ((ushort*)Cout)[(long)gm * N + gn] = f2bf(v);
                } else if (EPI == 1) {
                    v = fmaxf(v, 0.f);
                    v = 0.8f * v + 0.1f * bf2f(pre[(long)gm * N + gn])
                                 + 0.1f * bf2f(in0[(long)gm * N + gn]);
                    ((ushort*)Cout)[(long)gm * N + gn] = f2bf(v);
                } else {
                    v += bias[gn];
                    v = fmaxf(v, 0.f);
                    ((float*)Cout)[(long)gm * N + gn] = v;
                }
            }
        }
    }
}

// ---------------------------------------------------------------------------
// Gather + unweighted path-sum per (type,l) + weighted combine.
//   means[e,n,h] = sum_l w'[e,l,h] * sum_{p in type e} feats[paths[p,n,l], h]
// where w' is pre-scaled by 1/count_e (folded into registers).
// Block = 256 thr = 4 nodes x 64 lanes. Half-wave owns a type:
//   e = lane>>5, lane&31 = h-quad (4 channels, uint2 load = 8B).
// One load instruction fetches 2 rows (both halves) = 512B.
// Fast path ce==4 fully unrolls -> 32 independent gathers per node in flight.
// ---------------------------------------------------------------------------
__global__ __launch_bounds__(256) void gather_bf16(
    const uint* __restrict__ feats_u,   // [NN][64]  (bf16x2 packed)
    const int* __restrict__ paths,      // [P][NN][L]
    const int* __restrict__ ptypes,     // [P]
    const float* __restrict__ pw,       // [2][L][HID] f32
    uint* __restrict__ fout_u)          // [NN][128] (bf16x2 packed)
{
    const int tid = threadIdx.x;
    const int node = tid >> 6;
    const int lane = tid & 63;
    const int e = lane >> 5;
    const int hq = lane & 31;           // h-quad: channels hq*4 .. hq*4+3
    const int n = blockIdx.x * 4 + node;

    __shared__ int idx_l[4][N_TYPES][PATH_LEN][8];

    // path types (scalar-cached), counts, and this thread's staging slot
    int pt[N_PATHS];
#pragma unroll
    for (int p = 0; p < N_PATHS; ++p) pt[p] = ptypes[p];
    int cnt0 = 0, cnt1 = 0;
#pragma unroll
    for (int p = 0; p < N_PATHS; ++p) { if (pt[p] == 0) cnt0++; else cnt1++; }

    {
        int sp = lane >> 3, sl = lane & 7;
        int rank = 0;
#pragma unroll
        for (int p = 0; p < N_PATHS; ++p)
            if (p < sp && pt[p] == pt[sp]) rank++;
        idx_l[node][pt[sp]][sl][rank] = paths[((long)sp * NN + n) * PATH_LEN + sl];
    }
    __syncthreads();

    const int ce = e ? cnt1 : cnt0;
    const float inv = ce ? 1.f / (float)ce : 0.f;

    // per-lane weights for own type, pre-scaled by 1/ce (static reg array)
    float4 wv[PATH_LEN];
#pragma unroll
    for (int l = 0; l < PATH_LEN; ++l) {
        float4 t = *(const float4*)&pw[(e * PATH_LEN + l) * HID + hq * 4];
        wv[l].x = t.x * inv; wv[l].y = t.y * inv;
        wv[l].z = t.z * inv; wv[l].w = t.w * inv;
    }

    float4 acc = {0.f, 0.f, 0.f, 0.f};

    if (ce == 4) {
        // fast path: fully unrolled, 32 independent 8B gathers
#pragma unroll
        for (int l = 0; l < PATH_LEN; ++l) {
            int4 r4 = *(const int4*)&idx_l[node][e][l][0];
            uint2 v0 = *(const uint2*)(feats_u + (long)r4.x * 64 + hq * 2);
            uint2 v1 = *(const uint2*)(feats_u + (long)r4.y * 64 + hq * 2);
            uint2 v2 = *(const uint2*)(feats_u + (long)r4.z * 64 + hq * 2);
            uint2 v3 = *(const uint2*)(feats_u + (long)r4.w * 64 + hq * 2);
            float sx = bf2f((ushort)(v0.x & 0xffff)) + bf2f((ushort)(v1.x & 0xffff))
                     + bf2f((ushort)(v2.x & 0xffff)) + bf2f((ushort)(v3.x & 0xffff));
            float sy = bf2f((ushort)(v0.x >> 16)) + bf2f((ushort)(v1.x >> 16))
                     + bf2f((ushort)(v2.x >> 16)) + bf2f((ushort)(v3.x >> 16));
            float sz = bf2f((ushort)(v0.y & 0xffff)) + bf2f((ushort)(v1.y & 0xffff))
                     + bf2f((ushort)(v2.y & 0xffff)) + bf2f((ushort)(v3.y & 0xffff));
            float sw = bf2f((ushort)(v0.y >> 16)) + bf2f((ushort)(v1.y >> 16))
                     + bf2f((ushort)(v2.y >> 16)) + bf2f((ushort)(v3.y >> 16));
            acc.x += sx * wv[l].x;
            acc.y += sy * wv[l].y;
            acc.z += sz * wv[l].z;
            acc.w += sw * wv[l].w;
        }
    } else {
        // generic fallback (correct for any type distribution)
#pragma unroll
        for (int l = 0; l < PATH_LEN; ++l) {
            float sx = 0.f, sy = 0.f, sz = 0.f, sw = 0.f;
            for (int q = 0; q < ce; ++q) {
                int row = idx_l[node][e][l][q];
                uint2 v = *(const uint2*)(feats_u + (long)row * 64 + hq * 2);
                sx += bf2f((ushort)(v.x & 0xffff));
                sy += bf2f((ushort)(v.x >> 16));
                sz += bf2f((ushort)(v.y & 0xffff));
                sw += bf2f((ushort)(v.y >> 16));
            }
            acc.x += sx * wv[l].x;
            acc.y += sy * wv[l].y;
            acc.z += sz * wv[l].z;
            acc.w += sw * wv[l].w;
        }
    }

    uint2 o;
    o.x = (uint)f2bf(acc.x) | ((uint)f2bf(acc.y) << 16);
    o.y = (uint)f2bf(acc.z) | ((uint)f2bf(acc.w) << 16);
    *(uint2*)(fout_u + (long)n * 128 + e * 64 + hq * 2) = o;
}

// ---------------------------------------------------------------------------
extern "C" void kernel_launch(void* const* d_in, const int* in_sizes, int n_in,
                              void* d_out, int out_size, void* d_ws, size_t ws_size,
                              hipStream_t stream)
{
    const float* input_x      = (const float*)d_in[0];
    const int*   paths        = (const int*)d_in[1];
    const int*   path_types   = (const int*)d_in[2];
    const float* fc_in_w      = (const float*)d_in[3];
    const float* fc_in_b      = (const float*)d_in[4];
    const float* fc_out_w     = (const float*)d_in[5];
    const float* fc_out_b     = (const float*)d_in[6];
    const float* layer_fc_w   = (const float*)d_in[7];
    const float* path_weights = (const float*)d_in[8];
    float* out = (float*)d_out;

    char* p = (char*)d_ws;
    ushort* in_feats = (ushort*)p; p += (long)NN * HID * 2;               // 5.12 MB
    ushort* featsA   = (ushort*)p; p += (long)NN * HID * 2;
    ushort* featsB   = (ushort*)p; p += (long)NN * HID * 2;
    ushort* fout     = (ushort*)p; p += (long)NN * N_TYPES * HID * 2;     // 10.24 MB

    const int GG = (NN + 63) / 64;   // 313

    // in_feats = relu(x @ Win^T + b), fp32 operands converted while staging
    gemm_mfma<HID, IN_DIM, 0, true, true><<<GG, 256, 0, stream>>>(
        input_x, fc_in_w, fc_in_b, nullptr, nullptr, in_feats, NN);

    const ushort* src = in_feats;
    ushort* dsts[N_LAYERS] = {featsA, featsB, featsA, featsB};
    for (int i = 0; i < N_LAYERS; ++i) {
        gather_bf16<<<NN / 4, 256, 0, stream>>>(
            (const uint*)src, paths, path_types,
            path_weights + (long)i * N_TYPES * PATH_LEN * HID, (uint*)fout);
        gemm_mfma<HID, N_TYPES * HID, 1, false, true><<<GG, 256, 0, stream>>>(
            fout, layer_fc_w + (long)i * HID * N_TYPES * HID, nullptr,
            src, in_feats, dsts[i], NN);
        src = dsts[i];
    }

    gemm_mfma<OUT_DIM, HID, 2, false, true><<<GG, 256, 0, stream>>>(
        src, fc_out_w, fc_out_b, nullptr, nullptr, out, NN);
}